// Round 4
// baseline (89682.977 us; speedup 1.0000x reference)
//
#include <hip/hip_runtime.h>

#define VV    32000
#define EE    256
#define RSZ   1024
#define BB    64
#define TT    2048
#define NGRP  3
#define EPSLN 1e-5f

#define NBLK_PER_GRP 64
#define NBLK  (NBLK_PER_GRP * NGRP)   // 192 blocks, 1 per CU
#define NTHR  1024                    // 16 waves = 8 k-groups x 128 threads
#define SLAB  (BB * RSZ)

#define BAR_OFF (NGRP * 2 * SLAB)     // floats offset of barrier words in d_ws

// one k-step (4 k-values) of FMAs: 4 rows x 4 j x 2 cols
__device__ __forceinline__ void fma_step(const float4 (&b)[4], const float* wrow,
                                         float (&acc)[4][2]) {
#pragma unroll
    for (int j = 0; j < 4; ++j) {
        const float2 w = *reinterpret_cast<const float2*>(wrow + j * 16);
#pragma unroll
        for (int r = 0; r < 4; ++r) {
            const float a = reinterpret_cast<const float*>(&b[r])[j];
            acc[r][0] = fmaf(a, w.x, acc[r][0]);
            acc[r][1] = fmaf(a, w.y, acc[r][1]);
        }
    }
}

__device__ __forceinline__ void ld4x4(float4 (&b)[4], const float* const (&p)[4],
                                      int off) {
#pragma unroll
    for (int r = 0; r < 4; ++r)
        b[r] = *reinterpret_cast<const float4*>(p[r] + off);
}

__global__ __launch_bounds__(NTHR, 4)
void reservoir_main(const int*   __restrict__ x,        // [B,T]
                    const float* __restrict__ embed_w,  // [V,E]
                    const float* __restrict__ Win0,
                    const float* __restrict__ Win1,
                    const float* __restrict__ Win2,
                    const float* __restrict__ Rm0,
                    const float* __restrict__ Rm1,
                    const float* __restrict__ Rm2,
                    const float* __restrict__ ln_w,
                    const float* __restrict__ ln_b,
                    float*       __restrict__ states,
                    unsigned*    __restrict__ bar,
                    float*       __restrict__ out)
{
    const int blk   = blockIdx.x;
    const int grp   = blk >> 6;              // layer
    const int gb    = blk & 63;
    const int c0    = gb << 4;               // 16-col slice
    const int tid   = threadIdx.x;
    const int kg    = tid >> 7;              // 0..7
    const int idx   = tid & 127;
    const int rbase = (idx >> 3) << 2;       // 4 rows per lane
    const int cg2   = (idx & 7) << 1;        // col pair

    const float* Wl  = (grp == 0) ? Win0 : ((grp == 1) ? Win1 : Win2);
    const float* Rl  = (grp == 0) ? Rm0  : ((grp == 1) ? Rm1  : Rm2);
    const int    Kw  = (grp == 0) ? EE : RSZ;
    const int    Kw8 = Kw >> 3;              // per-kg input k-slice (32 or 128)
    const int    nW  = Kw8 >> 2;             // W-part k-steps (8 or 32)

    __shared__ float wlds[2048 * 16];        // 128 KB weight slab
    __shared__ float pbuf[8][32][18];        // partials

    for (int i = tid; i < RSZ * 16; i += NTHR) {
        const int k = i >> 4, c = i & 15;
        wlds[i] = Rl[(size_t)k * RSZ + c0 + c];
    }
    for (int i = tid; i < Kw * 16; i += NTHR) {
        const int k = i >> 4, c = i & 15;
        wlds[RSZ * 16 + i] = Wl[(size_t)k * RSZ + c0 + c];
    }
    __syncthreads();

    unsigned* arrive = bar;
    unsigned* epoch  = bar + 32;

    float* const sl = states + (size_t)grp * 2 * SLAB;
    const float* const wRb = wlds + (kg << 7) * 16 + cg2;
    const float* const wWb = wlds + (RSZ + kg * Kw8) * 16 + cg2;

    int xidx[4];
    if (grp == 0) {
#pragma unroll
        for (int r = 0; r < 4; ++r) xidx[r] = x[(rbase + r) * TT + 0];
    }

    for (int tick = 0; tick < TT + NGRP - 1; ++tick) {
        const int t = tick - grp;            // uniform per block
        if (0 <= t && t < TT) {
            const float* sprev = sl + (size_t)((t + 1) & 1) * SLAB;

            const float* aR[4];
#pragma unroll
            for (int r = 0; r < 4; ++r)
                aR[r] = sprev + (size_t)(rbase + r) * RSZ + (kg << 7);

            const float* aW[4];
            if (grp == 0) {
#pragma unroll
                for (int r = 0; r < 4; ++r)
                    aW[r] = embed_w + (size_t)xidx[r] * EE + kg * Kw8;
            } else {
                const float* cb = states + ((size_t)(grp - 1) * 2 + (t & 1)) * SLAB;
#pragma unroll
                for (int r = 0; r < 4; ++r)
                    aW[r] = cb + (size_t)(rbase + r) * RSZ + kg * Kw8;
            }

            float acc[4][2] = {{0.f,0.f},{0.f,0.f},{0.f,0.f},{0.f,0.f}};

            // depth-2 double-buffered, fused R+W pipeline
            float4 bR[2][4], bW[2][4];
            ld4x4(bR[0], aR, 0);
            ld4x4(bW[0], aW, 0);
            ld4x4(bR[1], aR, 4);
            ld4x4(bW[1], aW, 4);

            for (int it = 0; it < 32; it += 2) {
                // slot 0: k-step it
                fma_step(bR[0], wRb + it * 64, acc);
                ld4x4(bR[0], aR, (min(it + 2, 31)) << 2);
                if (it < nW) {
                    fma_step(bW[0], wWb + it * 64, acc);
                    ld4x4(bW[0], aW, (min(it + 2, nW - 1)) << 2);
                }
                // slot 1: k-step it+1
                fma_step(bR[1], wRb + (it + 1) * 64, acc);
                ld4x4(bR[1], aR, (min(it + 3, 31)) << 2);
                if (it + 1 < nW) {
                    fma_step(bW[1], wWb + (it + 1) * 64, acc);
                    ld4x4(bW[1], aW, (min(it + 3, nW - 1)) << 2);
                }
            }

            // prefetch next tick's token indices (layer 0 only)
            if (grp == 0 && t + 1 < TT) {
#pragma unroll
                for (int r = 0; r < 4; ++r) xidx[r] = x[(rbase + r) * TT + t + 1];
            }

            // ---- flat reduce over 8 k-groups, two row-halves ----
            float* sout = sl + (size_t)(t & 1) * SLAB;

            if (rbase < 32) {
#pragma unroll
                for (int r = 0; r < 4; ++r) {
                    const int row = rbase + r;
                    *reinterpret_cast<float2*>(&pbuf[kg][row][cg2 ^ (row & 12)])
                        = make_float2(acc[r][0], acc[r][1]);
                }
            }
            __syncthreads();
            if (tid < 512) {
                const int row = tid >> 4, col = tid & 15;
                float s = 0.f;
#pragma unroll
                for (int g = 0; g < 8; ++g) s += pbuf[g][row][col ^ (row & 12)];
                sout[(size_t)row * RSZ + c0 + col] = tanhf(s);
            }
            __syncthreads();
            if (rbase >= 32) {
#pragma unroll
                for (int r = 0; r < 4; ++r) {
                    const int row = rbase + r, rl = row & 31;
                    *reinterpret_cast<float2*>(&pbuf[kg][rl][cg2 ^ (rl & 12)])
                        = make_float2(acc[r][0], acc[r][1]);
                }
            }
            __syncthreads();
            if (tid < 512) {
                const int rl = tid >> 4, col = tid & 15;
                float s = 0.f;
#pragma unroll
                for (int g = 0; g < 8; ++g) s += pbuf[g][rl][col ^ (rl & 12)];
                sout[(size_t)(32 + rl) * RSZ + c0 + col] = tanhf(s);
            }
        }

        // ---- device-wide barrier (monotonic epoch) ----
        __syncthreads();
        if (tid == 0) {
            __threadfence();                 // release
            const unsigned target = (unsigned)(tick + 1);
            const unsigned prev = atomicAdd(arrive, 1u);
            if (prev == (unsigned)NBLK * target - 1u) {
                __hip_atomic_store(epoch, target, __ATOMIC_RELEASE,
                                   __HIP_MEMORY_SCOPE_AGENT);
            } else {
                while (__hip_atomic_load(epoch, __ATOMIC_RELAXED,
                                         __HIP_MEMORY_SCOPE_AGENT) < target)
                    __builtin_amdgcn_s_sleep(1);
            }
            __threadfence();                 // acquire
        }
        __syncthreads();
    }

    // ---- LayerNorm over h = s_2(T-1) (slot 1), blocks 0..63 ----
    if (blk < BB) {
        const float* h = states + ((size_t)2 * 2 + 1) * SLAB + (size_t)blk * RSZ;
        float* red = &pbuf[0][0][0];

        const float hv = h[tid];             // RSZ == NTHR
        float v = hv;
#pragma unroll
        for (int o = 32; o > 0; o >>= 1) v += __shfl_down(v, o, 64);
        if ((tid & 63) == 0) red[tid >> 6] = v;
        __syncthreads();
        if (tid == 0) {
            float s = 0.f;
#pragma unroll
            for (int i = 0; i < 16; ++i) s += red[i];
            red[20] = s / (float)RSZ;
        }
        __syncthreads();
        const float mu = red[20];
        const float d = hv - mu;
        v = d * d;
#pragma unroll
        for (int o = 32; o > 0; o >>= 1) v += __shfl_down(v, o, 64);
        __syncthreads();
        if ((tid & 63) == 0) red[tid >> 6] = v;
        __syncthreads();
        if (tid == 0) {
            float s = 0.f;
#pragma unroll
            for (int i = 0; i < 16; ++i) s += red[i];
            red[21] = rsqrtf(s / (float)RSZ + EPSLN);
        }
        __syncthreads();
        const float inv = red[21];
        out[blk * RSZ + tid] = d * inv * ln_w[tid] + ln_b[tid];
    }
}

extern "C" void kernel_launch(void* const* d_in, const int* in_sizes, int n_in,
                              void* d_out, int out_size, void* d_ws, size_t ws_size,
                              hipStream_t stream) {
    const int*   x       = (const int*)  d_in[0];
    const float* embed_w = (const float*)d_in[1];
    const float* Win0    = (const float*)d_in[2];
    const float* Win1    = (const float*)d_in[3];
    const float* Win2    = (const float*)d_in[4];
    const float* Rm0     = (const float*)d_in[5];
    const float* Rm1     = (const float*)d_in[6];
    const float* Rm2     = (const float*)d_in[7];
    const float* ln_w    = (const float*)d_in[8];
    const float* ln_b    = (const float*)d_in[9];
    float*       out     = (float*)d_out;
    float*       states  = (float*)d_ws;
    unsigned*    bar     = (unsigned*)((float*)d_ws + BAR_OFF);

    hipMemsetAsync(d_ws, 0, (size_t)BAR_OFF * sizeof(float) + 4096, stream);

    void* args[] = {
        (void*)&x, (void*)&embed_w,
        (void*)&Win0, (void*)&Win1, (void*)&Win2,
        (void*)&Rm0, (void*)&Rm1, (void*)&Rm2,
        (void*)&ln_w, (void*)&ln_b,
        (void*)&states, (void*)&bar, (void*)&out
    };
    hipLaunchCooperativeKernel(reinterpret_cast<void*>(reservoir_main),
                               dim3(NBLK), dim3(NTHR), args, 0, stream);
}